// Round 1
// baseline (117.589 us; speedup 1.0000x reference)
//
#include <hip/hip_runtime.h>

// Chamfer distance, B=8, N=M=8192, 3-D fp32 points — pre-encoded MFMA frags.
// d2 = xx + yy - 2x.y inside mfma_f32_32x32x16_bf16 via split-precision limbs
// packed along K (13/16 slots; absmax 0.0 in earlier rounds):
//   A row (query q):  [(-2q)h*3, (-2q)l*3, (-2q)h*3, qqh, qql, 1, 1, 0,0,0]
//   B col (target t): [ th*3,     th*3,     tl*3,    1, 1, tth, ttl, 0,0,0]
// R8 (this round): latency-bound fix. Grid 512->1024 (CT 8->4, RT 4->2,
// STRIPS 16->32) with __launch_bounds__(256,4): 4 blocks/CU = 4 waves/SIMD
// (was 2), exact fill 1024 = 256 CU x 4. Smaller acc state (32 regs vs 64)
// keeps total regs ~<=128 so accumulators stay VALU-addressable. Serial
// 16-deep min chain split into 4 parallel min3 chains (depth ~6).
// Fin fused via last-block counter. 2 dispatches, no memsets.

#define BB 8
#define NN 8192
#define NPTS (BB*NN)  // 65536
#define BLK 256
#define CCOLS 128     // cols per block
#define CT 4          // col-tiles per block
#define RT 2          // row-tiles per wave per strip
#define STRIPS 32     // 32 strips * 4 waves * 64 rows = 8192
#define GRID 1024     // dir(2) * b(8) * cc(64)

typedef __attribute__((ext_vector_type(8))) short bf16x8;
typedef __attribute__((ext_vector_type(16))) float f32x16;

__device__ __forceinline__ unsigned f2mono(float f) {
    unsigned u = __float_as_uint(f);
    return u ^ ((unsigned)((int)u >> 31) | 0x80000000u);
}
__device__ __forceinline__ float mono2f(unsigned m) {
    unsigned u = ((int)m >= 0) ? ~m : (m ^ 0x80000000u);
    return __uint_as_float(u);
}
__device__ __forceinline__ unsigned bfh(float v) {   // fp32 -> bf16 RNE
    unsigned u = __float_as_uint(v);
    u += 0x7FFFu + ((u >> 16) & 1u);
    return u >> 16;
}
__device__ __forceinline__ float bff(unsigned h) {
    return __uint_as_float(h << 16);
}
__device__ __forceinline__ unsigned pk(unsigned lo, unsigned hi) {
    return (lo & 0xFFFFu) | (hi << 16);
}

// grid 512, block 256: one thread per point (x: [0,NPTS), y: [NPTS,2*NPTS))
__global__ void prep_kernel(const float* __restrict__ x, const float* __restrict__ y,
                            uint4* __restrict__ afr, uint4* __restrict__ bfr,
                            unsigned* __restrict__ counter) {
    int i = blockIdx.x * BLK + threadIdx.x;
    if (i == 0) *counter = 0;
    const float* src = (i < NPTS) ? x : y;
    int j = (i < NPTS) ? i : i - NPTS;
    float c0 = src[3*j], c1 = src[3*j+1], c2 = src[3*j+2];
    float s2 = c0*c0 + c1*c1 + c2*c2;
    unsigned sh = bfh(s2), sl = bfh(s2 - bff(sh));
    float a0 = -2.f*c0, a1 = -2.f*c1, a2 = -2.f*c2;
    unsigned ah0 = bfh(a0), ah1 = bfh(a1), ah2 = bfh(a2);
    unsigned al0 = bfh(a0 - bff(ah0)), al1 = bfh(a1 - bff(ah1)), al2 = bfh(a2 - bff(ah2));
    unsigned bh0 = bfh(c0), bh1 = bfh(c1), bh2 = bfh(c2);
    unsigned bl0 = bfh(c0 - bff(bh0)), bl1 = bfh(c1 - bff(bh1)), bl2 = bfh(c2 - bff(bh2));
    const unsigned one = 0x3F80u;
    afr[2*i]   = make_uint4(pk(ah0,ah1), pk(ah2,al0), pk(al1,al2), pk(ah0,ah1));
    afr[2*i+1] = make_uint4(pk(ah2,sh),  pk(sl,one),  pk(one,0u),  0u);
    bfr[2*i]   = make_uint4(pk(bh0,bh1), pk(bh2,bh0), pk(bh1,bh2), pk(bl0,bl1));
    bfr[2*i+1] = make_uint4(pk(bl2,one), pk(one,sh),  pk(sl,0u),   0u);
}

__device__ __forceinline__ bf16x8 cvt(uint4 v) { return __builtin_bit_cast(bf16x8, v); }

// grid: 1024 = (dir<<9) | (b<<6) | cc ; block 256
__global__ __launch_bounds__(BLK, 4) void
main_kernel(const uint4* __restrict__ afr, const uint4* __restrict__ bfr,
            float* __restrict__ bpart, unsigned* __restrict__ counter,
            float* __restrict__ out) {
    __shared__ unsigned colmin[CCOLS];
    __shared__ float red[4];
    __shared__ float gg[8];
    __shared__ int lastflag;
    const int bi  = blockIdx.x;
    const int dir = bi >> 9;
    const int b   = (bi >> 6) & 7;
    const int cc  = bi & 63;
    const uint4* Af = afr + (dir ? 2*NPTS : 0);        // A rows: dir? y : x
    const uint4* Bf = bfr + (dir ? 0 : 2*NPTS);        // B cols: dir? x : y
    const int tid = threadIdx.x;
    const int lane = tid & 63, w = tid >> 6;
    const int m = lane & 31;
    const int hb = lane >> 5;

    if (tid < CCOLS) colmin[tid] = 0xFFFFFFFFu;  // waves co-resident; barrier after hot loop

    // this block's 4 B col-tile fragments -> registers (coalesced dwordx4)
    bf16x8 bf[CT];
#pragma unroll
    for (int ct = 0; ct < CT; ++ct) {
        int c = b * NN + cc * CCOLS + ct * 32 + m;
        bf[ct] = cvt(Bf[2*c + hb]);
    }

    f32x16 zro;
#pragma unroll
    for (int i = 0; i < 16; ++i) zro[i] = 0.f;

    float rm[CT];
#pragma unroll
    for (int ct = 0; ct < CT; ++ct) rm[ct] = 3.4e38f;

    const int rowbase = b * NN + w * 64 + m;
    uint4 cur[RT], nxt[RT];
#pragma unroll
    for (int t = 0; t < RT; ++t) cur[t] = Af[2*(rowbase + t*32) + hb];

#pragma unroll 1
    for (int s = 0; s < STRIPS; ++s) {
        const int np = (s + 1 < STRIPS) ? (s + 1) : s;   // prefetch next strip
#pragma unroll
        for (int t = 0; t < RT; ++t) nxt[t] = Af[2*(rowbase + np*256 + t*32) + hb];
        bf16x8 ca = cvt(cur[0]), cb = cvt(cur[1]);
#pragma unroll
        for (int ct = 0; ct < CT; ++ct) {
            f32x16 a0 = __builtin_amdgcn_mfma_f32_32x32x16_bf16(ca, bf[ct], zro, 0, 0, 0);
            f32x16 a1 = __builtin_amdgcn_mfma_f32_32x32x16_bf16(cb, bf[ct], zro, 0, 0, 0);
            // 4 parallel min3 chains (depth ~6) instead of one 16-deep chain
            float m0 = fminf(fminf(a0[0], a1[0]), rm[ct]);   // v_min3
            float m1 = fminf(a0[1], a1[1]);
            float m2 = fminf(a0[2], a1[2]);
            float m3 = fminf(a0[3], a1[3]);
#pragma unroll
            for (int r = 4; r < 16; r += 4) {
                m0 = fminf(fminf(a0[r],   a1[r]),   m0);     // v_min3
                m1 = fminf(fminf(a0[r+1], a1[r+1]), m1);
                m2 = fminf(fminf(a0[r+2], a1[r+2]), m2);
                m3 = fminf(fminf(a0[r+3], a1[r+3]), m3);
            }
            rm[ct] = fminf(fminf(m0, m1), fminf(m2, m3));
        }
#pragma unroll
        for (int t = 0; t < RT; ++t) cur[t] = nxt[t];
    }

    // merge row-halves in-wave, then across the 4 waves via small LDS atomics
#pragma unroll
    for (int ct = 0; ct < CT; ++ct) {
        float p = fminf(rm[ct], __shfl_xor(rm[ct], 32, 64));
        if (hb == 0) atomicMin(&colmin[ct * 32 + m], f2mono(p));
    }
    __syncthreads();

    // colmin[tid] (tid<128) is the FINAL min-d2 for col (cc*128 + tid)
    float d = (tid < CCOLS) ? sqrtf(fmaxf(mono2f(colmin[tid]), 0.f) + 1e-10f) : 0.f;
#pragma unroll
    for (int off = 32; off; off >>= 1) d += __shfl_down(d, off, 64);
    if (lane == 0) red[w] = d;
    __syncthreads();
    if (tid == 0) {
        float total = red[0] + red[1] + red[2] + red[3];
        atomicExch(&bpart[bi], total);        // device-scope coherent store
        __threadfence();
        unsigned old = atomicAdd(counter, 1u);
        lastflag = (old == (GRID - 1));
    }
    __syncthreads();

    if (lastflag) {                           // block-uniform
        // dir=0 partials: bpart[0..511]; dir=1: bpart[512..1023]
        float v0 = atomicAdd(&bpart[2*tid], 0.f) + atomicAdd(&bpart[2*tid+1], 0.f);
        float v1 = atomicAdd(&bpart[512 + 2*tid], 0.f) + atomicAdd(&bpart[512 + 2*tid+1], 0.f);
#pragma unroll
        for (int off = 16; off; off >>= 1) {
            v0 += __shfl_down(v0, off, 32);
            v1 += __shfl_down(v1, off, 32);
        }
        if ((tid & 31) == 0) gg[tid >> 5] = fmaxf(v0, v1);
        __syncthreads();
        if (tid == 0) {
            float acc = 0.f;
#pragma unroll
            for (int k = 0; k < 8; ++k) acc += gg[k];
            out[0] = acc * (1.0f / (float)NN);
        }
    }
}

extern "C" void kernel_launch(void* const* d_in, const int* in_sizes, int n_in,
                              void* d_out, int out_size, void* d_ws, size_t ws_size,
                              hipStream_t stream) {
    const float* x = (const float*)d_in[0];
    const float* y = (const float*)d_in[1];
    float* out = (float*)d_out;

    char* ws = (char*)d_ws;
    uint4* afr = (uint4*)ws;                     // 2*NPTS*2 uint4 = 4 MB
    uint4* bfr = afr + 4 * NPTS;                 // 4 MB
    float* bpart = (float*)(bfr + 4 * NPTS);     // 1024 floats
    unsigned* counter = (unsigned*)(bpart + GRID);

    prep_kernel<<<(2 * NPTS) / BLK, BLK, 0, stream>>>(x, y, afr, bfr, counter);
    main_kernel<<<GRID, BLK, 0, stream>>>(afr, bfr, bpart, counter, out);
}

// Round 2
// 99.965 us; speedup vs baseline: 1.1763x; 1.1763x over previous
//
#include <hip/hip_runtime.h>

// Chamfer distance, B=8, N=M=8192, 3-D fp32 points — pre-encoded MFMA frags.
// d2 = xx + yy - 2x.y inside mfma_f32_32x32x16_bf16 via split-precision limbs
// packed along K (13/16 slots; absmax 0.0 verified):
//   A row (query q):  [(-2q)h*3, (-2q)l*3, (-2q)h*3, qqh, qql, 1, 1, 0,0,0]
//   B col (target t): [ th*3,     th*3,     tl*3,    1, 1, tth, ttl, 0,0,0]
// R9: revert R8's occupancy experiment (4 blocks/CU starved registers ->
// serialized MFMA->VALU, 63us). Back to grid 512 / CT=8 / RT=4 / bounds(256,2)
// (46us proven) + NEW: explicit depth-2 software pipeline in the strip body.
// Two named accumulator sets (e*/o*): MFMAs for col-tile ct+1 are issued
// BEFORE the min-reduction of ct, so MFMA latency hides under the previous
// tile's VALU chain. All accumulator names static (no dynamic indexing).
// Fin fused via last-block counter. 2 dispatches, no memsets.

#define BB 8
#define NN 8192
#define NPTS (BB*NN)  // 65536
#define BLK 256
#define CCOLS 256
#define CT 8          // col-tiles per block
#define RT 4          // row-tiles per strip per wave
#define STRIPS 16     // 16 strips * 4 waves * 128 rows = 8192

typedef __attribute__((ext_vector_type(8))) short bf16x8;
typedef __attribute__((ext_vector_type(16))) float f32x16;

__device__ __forceinline__ unsigned f2mono(float f) {
    unsigned u = __float_as_uint(f);
    return u ^ ((unsigned)((int)u >> 31) | 0x80000000u);
}
__device__ __forceinline__ float mono2f(unsigned m) {
    unsigned u = ((int)m >= 0) ? ~m : (m ^ 0x80000000u);
    return __uint_as_float(u);
}
__device__ __forceinline__ unsigned bfh(float v) {   // fp32 -> bf16 RNE
    unsigned u = __float_as_uint(v);
    u += 0x7FFFu + ((u >> 16) & 1u);
    return u >> 16;
}
__device__ __forceinline__ float bff(unsigned h) {
    return __uint_as_float(h << 16);
}
__device__ __forceinline__ unsigned pk(unsigned lo, unsigned hi) {
    return (lo & 0xFFFFu) | (hi << 16);
}

// grid 512, block 256: one thread per point (x: [0,NPTS), y: [NPTS,2*NPTS))
__global__ void prep_kernel(const float* __restrict__ x, const float* __restrict__ y,
                            uint4* __restrict__ afr, uint4* __restrict__ bfr,
                            unsigned* __restrict__ counter) {
    int i = blockIdx.x * BLK + threadIdx.x;
    if (i == 0) *counter = 0;
    const float* src = (i < NPTS) ? x : y;
    int j = (i < NPTS) ? i : i - NPTS;
    float c0 = src[3*j], c1 = src[3*j+1], c2 = src[3*j+2];
    float s2 = c0*c0 + c1*c1 + c2*c2;
    unsigned sh = bfh(s2), sl = bfh(s2 - bff(sh));
    float a0 = -2.f*c0, a1 = -2.f*c1, a2 = -2.f*c2;
    unsigned ah0 = bfh(a0), ah1 = bfh(a1), ah2 = bfh(a2);
    unsigned al0 = bfh(a0 - bff(ah0)), al1 = bfh(a1 - bff(ah1)), al2 = bfh(a2 - bff(ah2));
    unsigned bh0 = bfh(c0), bh1 = bfh(c1), bh2 = bfh(c2);
    unsigned bl0 = bfh(c0 - bff(bh0)), bl1 = bfh(c1 - bff(bh1)), bl2 = bfh(c2 - bff(bh2));
    const unsigned one = 0x3F80u;
    afr[2*i]   = make_uint4(pk(ah0,ah1), pk(ah2,al0), pk(al1,al2), pk(ah0,ah1));
    afr[2*i+1] = make_uint4(pk(ah2,sh),  pk(sl,one),  pk(one,0u),  0u);
    bfr[2*i]   = make_uint4(pk(bh0,bh1), pk(bh2,bh0), pk(bh1,bh2), pk(bl0,bl1));
    bfr[2*i+1] = make_uint4(pk(bl2,one), pk(one,sh),  pk(sl,0u),   0u);
}

__device__ __forceinline__ bf16x8 cvt(uint4 v) { return __builtin_bit_cast(bf16x8, v); }

// Issue 4 row-tile MFMAs for one B col-tile into a named accumulator set.
#define ISSUE4(B, R0, R1, R2, R3)                                              \
    R0 = __builtin_amdgcn_mfma_f32_32x32x16_bf16(ca0, (B), zro, 0, 0, 0);      \
    R1 = __builtin_amdgcn_mfma_f32_32x32x16_bf16(ca1, (B), zro, 0, 0, 0);      \
    R2 = __builtin_amdgcn_mfma_f32_32x32x16_bf16(ca2, (B), zro, 0, 0, 0);      \
    R3 = __builtin_amdgcn_mfma_f32_32x32x16_bf16(ca3, (B), zro, 0, 0, 0);

// Reduce a 4-accumulator set (64 f32) into DST via 4 parallel v_min3 chains.
#define RED4(R0, R1, R2, R3, DST) do {                                         \
    float c0_ = (DST), c1_ = 3.4e38f, c2_ = 3.4e38f, c3_ = 3.4e38f;            \
    _Pragma("unroll")                                                          \
    for (int r = 0; r < 16; r += 4) {                                          \
        float t0_ = fminf(fminf(R0[r],   R1[r]),   R2[r]);                     \
        c0_ = fminf(fminf(t0_, R3[r]),   c0_);                                 \
        float t1_ = fminf(fminf(R0[r+1], R1[r+1]), R2[r+1]);                   \
        c1_ = fminf(fminf(t1_, R3[r+1]), c1_);                                 \
        float t2_ = fminf(fminf(R0[r+2], R1[r+2]), R2[r+2]);                   \
        c2_ = fminf(fminf(t2_, R3[r+2]), c2_);                                 \
        float t3_ = fminf(fminf(R0[r+3], R1[r+3]), R2[r+3]);                   \
        c3_ = fminf(fminf(t3_, R3[r+3]), c3_);                                 \
    }                                                                          \
    (DST) = fminf(fminf(c0_, c1_), fminf(c2_, c3_));                           \
} while (0)

// grid: 512 = (dir<<8) | (b<<5) | cc ; block 256
__global__ __launch_bounds__(BLK, 2) void
main_kernel(const uint4* __restrict__ afr, const uint4* __restrict__ bfr,
            float* __restrict__ bpart, unsigned* __restrict__ counter,
            float* __restrict__ out) {
    __shared__ unsigned colmin[CCOLS];
    __shared__ float red[4];
    __shared__ float gg[8];
    __shared__ int lastflag;
    const int bi  = blockIdx.x;
    const int dir = bi >> 8;
    const int b   = (bi >> 5) & 7;
    const int cc  = bi & 31;
    const uint4* Af = afr + (dir ? 2*NPTS : 0);        // A rows: dir? y : x
    const uint4* Bf = bfr + (dir ? 0 : 2*NPTS);        // B cols: dir? x : y
    const int tid = threadIdx.x;
    const int lane = tid & 63, w = tid >> 6;
    const int m = lane & 31;
    const int hb = lane >> 5;

    colmin[tid] = 0xFFFFFFFFu;       // barrier comes after the hot loop

    // this block's 8 B col-tile fragments -> registers (coalesced dwordx4)
    bf16x8 bf[CT];
#pragma unroll
    for (int ct = 0; ct < CT; ++ct) {
        int c = b * NN + cc * CCOLS + ct * 32 + m;
        bf[ct] = cvt(Bf[2*c + hb]);
    }

    f32x16 zro;
#pragma unroll
    for (int i = 0; i < 16; ++i) zro[i] = 0.f;

    float rm[CT];
#pragma unroll
    for (int ct = 0; ct < CT; ++ct) rm[ct] = 3.4e38f;

    const int rowbase = b * NN + w * 128 + m;
    uint4 cur[RT], nxt[RT];
#pragma unroll
    for (int t = 0; t < RT; ++t) cur[t] = Af[2*(rowbase + t*32) + hb];

#pragma unroll 1
    for (int s = 0; s < STRIPS; ++s) {
        const int np = (s + 1 < STRIPS) ? (s + 1) : s;   // prefetch next strip
#pragma unroll
        for (int t = 0; t < RT; ++t) nxt[t] = Af[2*(rowbase + np*512 + t*32) + hb];

        const bf16x8 ca0 = cvt(cur[0]), ca1 = cvt(cur[1]);
        const bf16x8 ca2 = cvt(cur[2]), ca3 = cvt(cur[3]);

        // Depth-2 software pipeline: while set X is being min-reduced,
        // set Y's 4 MFMAs are already in the matrix pipe.
        f32x16 e0, e1, e2, e3, o0, o1, o2, o3;
        ISSUE4(bf[0], e0, e1, e2, e3);
        ISSUE4(bf[1], o0, o1, o2, o3);
        RED4(e0, e1, e2, e3, rm[0]);  ISSUE4(bf[2], e0, e1, e2, e3);
        RED4(o0, o1, o2, o3, rm[1]);  ISSUE4(bf[3], o0, o1, o2, o3);
        RED4(e0, e1, e2, e3, rm[2]);  ISSUE4(bf[4], e0, e1, e2, e3);
        RED4(o0, o1, o2, o3, rm[3]);  ISSUE4(bf[5], o0, o1, o2, o3);
        RED4(e0, e1, e2, e3, rm[4]);  ISSUE4(bf[6], e0, e1, e2, e3);
        RED4(o0, o1, o2, o3, rm[5]);  ISSUE4(bf[7], o0, o1, o2, o3);
        RED4(e0, e1, e2, e3, rm[6]);
        RED4(o0, o1, o2, o3, rm[7]);

#pragma unroll
        for (int t = 0; t < RT; ++t) cur[t] = nxt[t];
    }

    // merge K-halves in-wave, then across the 4 waves via small LDS atomics
#pragma unroll
    for (int ct = 0; ct < CT; ++ct) {
        float p = fminf(rm[ct], __shfl_xor(rm[ct], 32, 64));
        if (hb == 0) atomicMin(&colmin[ct * 32 + m], f2mono(p));
    }
    __syncthreads();

    // colmin[tid] is the FINAL min-d2 for col (cc*256 + tid)
    float d = sqrtf(fmaxf(mono2f(colmin[tid]), 0.f) + 1e-10f);
#pragma unroll
    for (int off = 32; off; off >>= 1) d += __shfl_down(d, off, 64);
    if (lane == 0) red[w] = d;
    __syncthreads();
    if (tid == 0) {
        float total = red[0] + red[1] + red[2] + red[3];
        atomicExch(&bpart[bi], total);        // device-scope coherent store
        __threadfence();
        unsigned old = atomicAdd(counter, 1u);
        lastflag = (old == 511u);
    }
    __syncthreads();

    if (lastflag) {                           // block-uniform
        float v0 = atomicAdd(&bpart[tid], 0.f);        // dir=0, group=tid>>5
        float v1 = atomicAdd(&bpart[256 + tid], 0.f);  // dir=1
#pragma unroll
        for (int off = 16; off; off >>= 1) {
            v0 += __shfl_down(v0, off, 32);
            v1 += __shfl_down(v1, off, 32);
        }
        if ((tid & 31) == 0) gg[tid >> 5] = fmaxf(v0, v1);
        __syncthreads();
        if (tid == 0) {
            float acc = 0.f;
#pragma unroll
            for (int k = 0; k < 8; ++k) acc += gg[k];
            out[0] = acc * (1.0f / (float)NN);
        }
    }
}

extern "C" void kernel_launch(void* const* d_in, const int* in_sizes, int n_in,
                              void* d_out, int out_size, void* d_ws, size_t ws_size,
                              hipStream_t stream) {
    const float* x = (const float*)d_in[0];
    const float* y = (const float*)d_in[1];
    float* out = (float*)d_out;

    char* ws = (char*)d_ws;
    uint4* afr = (uint4*)ws;                     // 2*NPTS*2 uint4 = 4 MB
    uint4* bfr = afr + 4 * NPTS;                 // 4 MB
    float* bpart = (float*)(bfr + 4 * NPTS);     // 512 floats
    unsigned* counter = (unsigned*)(bpart + 512);

    prep_kernel<<<(2 * NPTS) / BLK, BLK, 0, stream>>>(x, y, afr, bfr, counter);
    main_kernel<<<512, BLK, 0, stream>>>(afr, bfr, bpart, counter, out);
}

// Round 3
// 97.589 us; speedup vs baseline: 1.2049x; 1.0243x over previous
//
#include <hip/hip_runtime.h>

// Chamfer distance, B=8, N=M=8192, 3-D fp32 points — pre-encoded MFMA frags.
// d2 = xx + yy - 2x.y inside mfma_f32_32x32x16_bf16 via split-precision limbs
// packed along K (13/16 slots; absmax 0.0 verified):
//   A row (query q):  [(-2q)h*3, (-2q)l*3, (-2q)h*3, qqh, qql, 1, 1, 0,0,0]
//   B col (target t): [ th*3,     th*3,     tl*3,    1, 1, tth, ttl, 0,0,0]
// R10: R9's depth-2 software pipeline was DEFEATED by the scheduler
// (VGPR_Count stayed 76 -> compiler sank each RED4 next to its ISSUE4,
// single live acc set, full MFMA-latency stall per tile). This round pins
// the pipeline with __builtin_amdgcn_sched_barrier(0) at phase boundaries:
// RED4 of set X cannot cross the barrier to reach its ISSUE4, so BOTH acc
// sets stay live (expect VGPR >=160) and set-Y's MFMAs execute in the
// matrix pipe while set-X is min-reduced on the VALU.
// Geometry: grid 512 / CT=8 / RT=4 / bounds(256,2) — 46us proven base.
// Fin fused via last-block counter. 2 dispatches, no memsets.

#define BB 8
#define NN 8192
#define NPTS (BB*NN)  // 65536
#define BLK 256
#define CCOLS 256
#define CT 8          // col-tiles per block
#define RT 4          // row-tiles per strip per wave
#define STRIPS 16     // 16 strips * 4 waves * 128 rows = 8192

typedef __attribute__((ext_vector_type(8))) short bf16x8;
typedef __attribute__((ext_vector_type(16))) float f32x16;

__device__ __forceinline__ unsigned f2mono(float f) {
    unsigned u = __float_as_uint(f);
    return u ^ ((unsigned)((int)u >> 31) | 0x80000000u);
}
__device__ __forceinline__ float mono2f(unsigned m) {
    unsigned u = ((int)m >= 0) ? ~m : (m ^ 0x80000000u);
    return __uint_as_float(u);
}
__device__ __forceinline__ unsigned bfh(float v) {   // fp32 -> bf16 RNE
    unsigned u = __float_as_uint(v);
    u += 0x7FFFu + ((u >> 16) & 1u);
    return u >> 16;
}
__device__ __forceinline__ float bff(unsigned h) {
    return __uint_as_float(h << 16);
}
__device__ __forceinline__ unsigned pk(unsigned lo, unsigned hi) {
    return (lo & 0xFFFFu) | (hi << 16);
}

// grid 512, block 256: one thread per point (x: [0,NPTS), y: [NPTS,2*NPTS))
__global__ void prep_kernel(const float* __restrict__ x, const float* __restrict__ y,
                            uint4* __restrict__ afr, uint4* __restrict__ bfr,
                            unsigned* __restrict__ counter) {
    int i = blockIdx.x * BLK + threadIdx.x;
    if (i == 0) *counter = 0;
    const float* src = (i < NPTS) ? x : y;
    int j = (i < NPTS) ? i : i - NPTS;
    float c0 = src[3*j], c1 = src[3*j+1], c2 = src[3*j+2];
    float s2 = c0*c0 + c1*c1 + c2*c2;
    unsigned sh = bfh(s2), sl = bfh(s2 - bff(sh));
    float a0 = -2.f*c0, a1 = -2.f*c1, a2 = -2.f*c2;
    unsigned ah0 = bfh(a0), ah1 = bfh(a1), ah2 = bfh(a2);
    unsigned al0 = bfh(a0 - bff(ah0)), al1 = bfh(a1 - bff(ah1)), al2 = bfh(a2 - bff(ah2));
    unsigned bh0 = bfh(c0), bh1 = bfh(c1), bh2 = bfh(c2);
    unsigned bl0 = bfh(c0 - bff(bh0)), bl1 = bfh(c1 - bff(bh1)), bl2 = bfh(c2 - bff(bh2));
    const unsigned one = 0x3F80u;
    afr[2*i]   = make_uint4(pk(ah0,ah1), pk(ah2,al0), pk(al1,al2), pk(ah0,ah1));
    afr[2*i+1] = make_uint4(pk(ah2,sh),  pk(sl,one),  pk(one,0u),  0u);
    bfr[2*i]   = make_uint4(pk(bh0,bh1), pk(bh2,bh0), pk(bh1,bh2), pk(bl0,bl1));
    bfr[2*i+1] = make_uint4(pk(bl2,one), pk(one,sh),  pk(sl,0u),   0u);
}

__device__ __forceinline__ bf16x8 cvt(uint4 v) { return __builtin_bit_cast(bf16x8, v); }

#define SB() __builtin_amdgcn_sched_barrier(0)

// Issue 4 row-tile MFMAs for one B col-tile into a named accumulator set.
#define ISSUE4(B, R0, R1, R2, R3)                                              \
    R0 = __builtin_amdgcn_mfma_f32_32x32x16_bf16(ca0, (B), zro, 0, 0, 0);      \
    R1 = __builtin_amdgcn_mfma_f32_32x32x16_bf16(ca1, (B), zro, 0, 0, 0);      \
    R2 = __builtin_amdgcn_mfma_f32_32x32x16_bf16(ca2, (B), zro, 0, 0, 0);      \
    R3 = __builtin_amdgcn_mfma_f32_32x32x16_bf16(ca3, (B), zro, 0, 0, 0);

// Reduce a 4-accumulator set (64 f32) into DST via 4 parallel v_min3 chains.
#define RED4(R0, R1, R2, R3, DST) do {                                         \
    float c0_ = (DST), c1_ = 3.4e38f, c2_ = 3.4e38f, c3_ = 3.4e38f;            \
    _Pragma("unroll")                                                          \
    for (int r = 0; r < 16; r += 4) {                                          \
        float t0_ = fminf(fminf(R0[r],   R1[r]),   R2[r]);                     \
        c0_ = fminf(fminf(t0_, R3[r]),   c0_);                                 \
        float t1_ = fminf(fminf(R0[r+1], R1[r+1]), R2[r+1]);                   \
        c1_ = fminf(fminf(t1_, R3[r+1]), c1_);                                 \
        float t2_ = fminf(fminf(R0[r+2], R1[r+2]), R2[r+2]);                   \
        c2_ = fminf(fminf(t2_, R3[r+2]), c2_);                                 \
        float t3_ = fminf(fminf(R0[r+3], R1[r+3]), R2[r+3]);                   \
        c3_ = fminf(fminf(t3_, R3[r+3]), c3_);                                 \
    }                                                                          \
    (DST) = fminf(fminf(c0_, c1_), fminf(c2_, c3_));                           \
} while (0)

// grid: 512 = (dir<<8) | (b<<5) | cc ; block 256
__global__ __launch_bounds__(BLK, 2) void
main_kernel(const uint4* __restrict__ afr, const uint4* __restrict__ bfr,
            float* __restrict__ bpart, unsigned* __restrict__ counter,
            float* __restrict__ out) {
    __shared__ unsigned colmin[CCOLS];
    __shared__ float red[4];
    __shared__ float gg[8];
    __shared__ int lastflag;
    const int bi  = blockIdx.x;
    const int dir = bi >> 8;
    const int b   = (bi >> 5) & 7;
    const int cc  = bi & 31;
    const uint4* Af = afr + (dir ? 2*NPTS : 0);        // A rows: dir? y : x
    const uint4* Bf = bfr + (dir ? 0 : 2*NPTS);        // B cols: dir? x : y
    const int tid = threadIdx.x;
    const int lane = tid & 63, w = tid >> 6;
    const int m = lane & 31;
    const int hb = lane >> 5;

    colmin[tid] = 0xFFFFFFFFu;       // barrier comes after the hot loop

    // this block's 8 B col-tile fragments -> registers (coalesced dwordx4)
    bf16x8 bf[CT];
#pragma unroll
    for (int ct = 0; ct < CT; ++ct) {
        int c = b * NN + cc * CCOLS + ct * 32 + m;
        bf[ct] = cvt(Bf[2*c + hb]);
    }

    f32x16 zro;
#pragma unroll
    for (int i = 0; i < 16; ++i) zro[i] = 0.f;

    float rm[CT];
#pragma unroll
    for (int ct = 0; ct < CT; ++ct) rm[ct] = 3.4e38f;

    const int rowbase = b * NN + w * 128 + m;
    uint4 cur[RT], nxt[RT];
#pragma unroll
    for (int t = 0; t < RT; ++t) cur[t] = Af[2*(rowbase + t*32) + hb];

#pragma unroll 1
    for (int s = 0; s < STRIPS; ++s) {
        const int np = (s + 1 < STRIPS) ? (s + 1) : s;   // prefetch next strip
#pragma unroll
        for (int t = 0; t < RT; ++t) nxt[t] = Af[2*(rowbase + np*512 + t*32) + hb];

        const bf16x8 ca0 = cvt(cur[0]), ca1 = cvt(cur[1]);
        const bf16x8 ca2 = cvt(cur[2]), ca3 = cvt(cur[3]);

        // Depth-2 software pipeline, PINNED with sched_barrier(0) so the
        // scheduler cannot collapse it: while set X is min-reduced on the
        // VALU, set Y's 4 MFMAs execute in the matrix pipe.
        f32x16 e0, e1, e2, e3, o0, o1, o2, o3;
        ISSUE4(bf[0], e0, e1, e2, e3);
        ISSUE4(bf[1], o0, o1, o2, o3);
        SB();
        RED4(e0, e1, e2, e3, rm[0]);  ISSUE4(bf[2], e0, e1, e2, e3);
        SB();
        RED4(o0, o1, o2, o3, rm[1]);  ISSUE4(bf[3], o0, o1, o2, o3);
        SB();
        RED4(e0, e1, e2, e3, rm[2]);  ISSUE4(bf[4], e0, e1, e2, e3);
        SB();
        RED4(o0, o1, o2, o3, rm[3]);  ISSUE4(bf[5], o0, o1, o2, o3);
        SB();
        RED4(e0, e1, e2, e3, rm[4]);  ISSUE4(bf[6], e0, e1, e2, e3);
        SB();
        RED4(o0, o1, o2, o3, rm[5]);  ISSUE4(bf[7], o0, o1, o2, o3);
        SB();
        RED4(e0, e1, e2, e3, rm[6]);
        RED4(o0, o1, o2, o3, rm[7]);

#pragma unroll
        for (int t = 0; t < RT; ++t) cur[t] = nxt[t];
    }

    // merge K-halves in-wave, then across the 4 waves via small LDS atomics
#pragma unroll
    for (int ct = 0; ct < CT; ++ct) {
        float p = fminf(rm[ct], __shfl_xor(rm[ct], 32, 64));
        if (hb == 0) atomicMin(&colmin[ct * 32 + m], f2mono(p));
    }
    __syncthreads();

    // colmin[tid] is the FINAL min-d2 for col (cc*256 + tid)
    float d = sqrtf(fmaxf(mono2f(colmin[tid]), 0.f) + 1e-10f);
#pragma unroll
    for (int off = 32; off; off >>= 1) d += __shfl_down(d, off, 64);
    if (lane == 0) red[w] = d;
    __syncthreads();
    if (tid == 0) {
        float total = red[0] + red[1] + red[2] + red[3];
        atomicExch(&bpart[bi], total);        // device-scope coherent store
        __threadfence();
        unsigned old = atomicAdd(counter, 1u);
        lastflag = (old == 511u);
    }
    __syncthreads();

    if (lastflag) {                           // block-uniform
        float v0 = atomicAdd(&bpart[tid], 0.f);        // dir=0, group=tid>>5
        float v1 = atomicAdd(&bpart[256 + tid], 0.f);  // dir=1
#pragma unroll
        for (int off = 16; off; off >>= 1) {
            v0 += __shfl_down(v0, off, 32);
            v1 += __shfl_down(v1, off, 32);
        }
        if ((tid & 31) == 0) gg[tid >> 5] = fmaxf(v0, v1);
        __syncthreads();
        if (tid == 0) {
            float acc = 0.f;
#pragma unroll
            for (int k = 0; k < 8; ++k) acc += gg[k];
            out[0] = acc * (1.0f / (float)NN);
        }
    }
}

extern "C" void kernel_launch(void* const* d_in, const int* in_sizes, int n_in,
                              void* d_out, int out_size, void* d_ws, size_t ws_size,
                              hipStream_t stream) {
    const float* x = (const float*)d_in[0];
    const float* y = (const float*)d_in[1];
    float* out = (float*)d_out;

    char* ws = (char*)d_ws;
    uint4* afr = (uint4*)ws;                     // 2*NPTS*2 uint4 = 4 MB
    uint4* bfr = afr + 4 * NPTS;                 // 4 MB
    float* bpart = (float*)(bfr + 4 * NPTS);     // 512 floats
    unsigned* counter = (unsigned*)(bpart + 512);

    prep_kernel<<<(2 * NPTS) / BLK, BLK, 0, stream>>>(x, y, afr, bfr, counter);
    main_kernel<<<512, BLK, 0, stream>>>(afr, bfr, bpart, counter, out);
}